// Round 1
// 938.157 us; speedup vs baseline: 1.0299x; 1.0299x over previous
//
#include <hip/hip_runtime.h>
#include <math.h>

// ---------------------------------------------------------------------------
// NeuS-style fused renderer, R4.
//  - Activations kept in LDS as pre-split f16 hi/lo planes (split once at the
//    producing epilogue; consumer GEMM loops do zero split VALU).
//  - N=256 GEMMs (P2/P3/P6/P8) use v_mfma_f32_32x32x16_f16: half the MFMA
//    instructions and half the per-wave B L2 traffic vs 16x16x32.
//  - K loops are template-constant and fully unrolled so B loads pipeline.
//  - ReLU epilogues clamp positives to >=1e-4 so the hi-plane sign is an
//    exact (h>0) gradient gate.
// ---------------------------------------------------------------------------

#define TILE 32
#define NTHREADS 512
#define LDP 264     // act plane stride (halves): 132 dwords = 4 mod 32 banks
#define LDE 72      // enc plane stride (halves)
#define LDCIN 40    // cin plane stride (halves)
#define PI_F 3.14159265358979323846f

typedef _Float16 half8 __attribute__((ext_vector_type(8)));
typedef float f32x4 __attribute__((ext_vector_type(4)));
typedef float f32x16 __attribute__((ext_vector_type(16)));

struct alignas(16) SMemK2 {
    _Float16 a0h[TILE * LDP];   // h0 -> g1 -> cin(overlay)
    _Float16 a0l[TILE * LDP];
    _Float16 a1h[TILE * LDP];   // h1 -> g0(cols 0..63) -> hc
    _Float16 a1l[TILE * LDP];
    _Float16 ench[TILE * LDE];  // [x(3), sin/cos(36), 0-pad..63]
    _Float16 encl[TILE * LDE];
    float feats[TILE * 16];
    float pts [TILE * 4];
    float dirs[TILE * 4];
    float nrm [TILE * 4];
    _Float16 w2h[256];          // split Wg2[:,0]
    _Float16 w2l[256];
};  // 81408 B -> 2 blocks/CU

__device__ __forceinline__ void splitst(float v, _Float16* ph, _Float16* pl) {
    _Float16 h = (_Float16)v;
    *ph = h;
    *pl = (_Float16)(v - (float)h);
}

__device__ __forceinline__ f32x16 zero16() {
    f32x16 z;
#pragma unroll
    for (int i = 0; i < 16; ++i) z[i] = 0.f;
    return z;
}

// 32x32 output tile per wave, K = KITERS*16, cols nt*32..+32.
// A: split planes in LDS. B packed: hi8|lo8 per (nt,kit,lane).
// AMASK: A := (h1>0) ? wg2c0 : 0 (A planes hold h1; hi sign is exact gate).
// CMASK: epilogue gates by old C hi-plane sign (h0>0).
template<int KITERS, bool BIAS, bool RELU, bool AMASK, bool CMASK>
__device__ __forceinline__ void gemm32(
    const _Float16* Ah, const _Float16* Al, const int lda,
    const _Float16* w2h, const _Float16* w2l,
    const _Float16* __restrict__ Bp, const float* __restrict__ bias,
    _Float16* Ch, _Float16* Cl, const int ldc,
    const int lane, const int nt)
{
    f32x16 acc0 = zero16(), acc1 = zero16();
    const int row  = lane & 31;
    const int koff = (lane >> 5) * 8;
    const _Float16* ahb = Ah + row * lda + koff;
    const _Float16* alb = Al + row * lda + koff;
    const _Float16* bbase = Bp + ((size_t)nt * KITERS * 64 + lane) * 16;
#pragma unroll
    for (int kit = 0; kit < KITERS; ++kit) {
        half8 ah, al;
        if (AMASK) {
            half8 mh = *(const half8*)(ahb + kit * 16);
            half8 wh = *(const half8*)(w2h + kit * 16 + koff);
            half8 wl = *(const half8*)(w2l + kit * 16 + koff);
#pragma unroll
            for (int j = 0; j < 8; ++j) {
                bool m = mh[j] > (_Float16)0.f;
                ah[j] = m ? wh[j] : (_Float16)0.f;
                al[j] = m ? wl[j] : (_Float16)0.f;
            }
        } else {
            ah = *(const half8*)(ahb + kit * 16);
            al = *(const half8*)(alb + kit * 16);
        }
        const _Float16* bp = bbase + (size_t)kit * 1024;
        half8 bh = *(const half8*)bp;
        half8 bl = *(const half8*)(bp + 8);
        if (kit & 1) {
            acc1 = __builtin_amdgcn_mfma_f32_32x32x16_f16(al, bh, acc1, 0, 0, 0);
            acc1 = __builtin_amdgcn_mfma_f32_32x32x16_f16(ah, bl, acc1, 0, 0, 0);
            acc1 = __builtin_amdgcn_mfma_f32_32x32x16_f16(ah, bh, acc1, 0, 0, 0);
        } else {
            acc0 = __builtin_amdgcn_mfma_f32_32x32x16_f16(al, bh, acc0, 0, 0, 0);
            acc0 = __builtin_amdgcn_mfma_f32_32x32x16_f16(ah, bl, acc0, 0, 0, 0);
            acc0 = __builtin_amdgcn_mfma_f32_32x32x16_f16(ah, bh, acc0, 0, 0, 0);
        }
    }
    const int col = lane & 31;
    const int rb  = (lane >> 5) * 4;
    const int jc  = nt * 32 + col;
    const float bs = BIAS ? bias[jc] : 0.f;
#pragma unroll
    for (int r = 0; r < 16; ++r) {
        const int srow = (r & 3) + 8 * (r >> 2) + rb;
        float v = acc0[r] + acc1[r] + bs;
        if (RELU) v = (v > 0.f) ? fmaxf(v, 1e-4f) : 0.f;
        if (CMASK) { if (!((float)Ch[srow * ldc + jc] > 0.f)) v = 0.f; }
        _Float16 h = (_Float16)v;
        Ch[srow * ldc + jc] = h;
        Cl[srow * ldc + jc] = (_Float16)(v - (float)h);
    }
}

// 16x16 path (P7): rows mt*16..+16, cols (ntbase..+NTPW)*16, split-plane A.
template<int KITERS, int NTPW>
__device__ __forceinline__ void gemm16(
    const _Float16* Ah, const _Float16* Al, const int lda,
    const _Float16* __restrict__ Bp,
    _Float16* Ch, _Float16* Cl, const int ldc,
    const int lane, const int mt, const int ntbase)
{
    f32x4 acc[NTPW];
#pragma unroll
    for (int t = 0; t < NTPW; ++t) acc[t] = (f32x4){0.f, 0.f, 0.f, 0.f};
    const int m  = mt * 16 + (lane & 15);
    const int q8 = (lane >> 4) * 8;
    const _Float16* ahb = Ah + m * lda + q8;
    const _Float16* alb = Al + m * lda + q8;
    const _Float16* bbase = Bp + ((size_t)ntbase * KITERS * 64 + lane) * 16;
#pragma unroll
    for (int kit = 0; kit < KITERS; ++kit) {
        half8 ah = *(const half8*)(ahb + kit * 32);
        half8 al = *(const half8*)(alb + kit * 32);
        const _Float16* bp = bbase + (size_t)kit * 1024;
#pragma unroll
        for (int t = 0; t < NTPW; ++t) {
            const _Float16* bt = bp + (size_t)t * KITERS * 1024;
            half8 bh = *(const half8*)bt;
            half8 bl = *(const half8*)(bt + 8);
            acc[t] = __builtin_amdgcn_mfma_f32_16x16x32_f16(al, bh, acc[t], 0, 0, 0);
            acc[t] = __builtin_amdgcn_mfma_f32_16x16x32_f16(ah, bl, acc[t], 0, 0, 0);
            acc[t] = __builtin_amdgcn_mfma_f32_16x16x32_f16(ah, bh, acc[t], 0, 0, 0);
        }
    }
    const int col = lane & 15, q = lane >> 4;
#pragma unroll
    for (int t = 0; t < NTPW; ++t) {
        const int j = (ntbase + t) * 16 + col;
#pragma unroll
        for (int r = 0; r < 4; ++r) {
            const int s = mt * 16 + q * 4 + r;
            float v = acc[t][r];
            _Float16 h = (_Float16)v;
            Ch[s * ldc + j] = h;
            Cl[s * ldc + j] = (_Float16)(v - (float)h);
        }
    }
}

// ---------------- K0: pack weights to hi|lo B-fragment layouts --------------
// modes 0,1,2,4 -> 32x32x16 layout; modes 3,5,6 -> 16x16x32 layout.
__global__ __launch_bounds__(256) void k0_pack(
    const float* __restrict__ Wg0, const float* __restrict__ Wg1,
    const float* __restrict__ Wg2, const float* __restrict__ Wc0,
    const float* __restrict__ Wc1,
    _Float16* __restrict__ Wg0p, _Float16* __restrict__ Wg1p,
    _Float16* __restrict__ Wg1Tp, _Float16* __restrict__ Wg0Tp,
    _Float16* __restrict__ Wc0p, _Float16* __restrict__ Wg2p,
    _Float16* __restrict__ Wc1p)
{
    int gid = blockIdx.x * 256 + threadIdx.x;
    if (gid >= 180224) return;
    int idx, kiters, mode;
    _Float16* dst;
    if      (gid <  16384) { idx = gid;          kiters = 4;  dst = Wg0p;  mode = 0; }
    else if (gid <  81920) { idx = gid -  16384; kiters = 16; dst = Wg1p;  mode = 1; }
    else if (gid < 147456) { idx = gid -  81920; kiters = 16; dst = Wg1Tp; mode = 2; }
    else if (gid < 163840) { idx = gid - 147456; kiters = 8;  dst = Wg0Tp; mode = 3; }
    else if (gid < 172032) { idx = gid - 163840; kiters = 2;  dst = Wc0p;  mode = 4; }
    else if (gid < 176128) { idx = gid - 172032; kiters = 8;  dst = Wg2p;  mode = 5; }
    else                   { idx = gid - 176128; kiters = 8;  dst = Wc1p;  mode = 6; }
    const bool p32 = (mode == 0 || mode == 1 || mode == 2 || mode == 4);
    int j = idx & 7, lane = (idx >> 3) & 63, rest = idx >> 9;
    int kit = rest % kiters, nt = rest / kiters;
    int k, n;
    if (p32) { k = kit * 16 + ((lane >> 5) << 3) + j; n = (nt << 5) + (lane & 31); }
    else     { k = kit * 32 + ((lane >> 4) << 3) + j; n = (nt << 4) + (lane & 15); }
    float val = 0.f;
    switch (mode) {
        case 0: val = (k < 39) ? Wg0[k * 256 + n] : 0.f; break;
        case 1: val = Wg1[k * 256 + n]; break;
        case 2: val = Wg1[n * 256 + k]; break;                  // Wg1^T
        case 3: val = (n < 39) ? Wg0[n * 256 + k] : 0.f; break; // Wg0^T
        case 4: val = (k < 25) ? Wc0[k * 256 + n] : 0.f; break;
        case 5: val = Wg2[k * 16 + n]; break;
        case 6: val = (n < 3) ? Wc1[k * 3 + n] : 0.f; break;
    }
    _Float16 h = (_Float16)val;
    _Float16 l = (_Float16)(val - (float)h);
    int off = ((nt * kiters + kit) * 64 + lane) * 16 + j;
    dst[off] = h;
    dst[off + 8] = l;
}

// ---------------- K2: the fused MLP (8 waves) ------------------------------
__global__ __launch_bounds__(512, 4) void k2_mlp(
    const float* __restrict__ rays_o, const float* __restrict__ rays_d,
    const int*   __restrict__ ray_idx, const float* __restrict__ t_starts,
    const float* __restrict__ s_var,
    const float* __restrict__ bg0, const float* __restrict__ bg1,
    const float* __restrict__ Wg2, const float* __restrict__ bg2,
    const float* __restrict__ bc0, const float* __restrict__ bc1,
    const _Float16* __restrict__ Wg0p, const _Float16* __restrict__ Wg1p,
    const _Float16* __restrict__ Wg1Tp, const _Float16* __restrict__ Wg0Tp,
    const _Float16* __restrict__ Wc0p, const _Float16* __restrict__ Wg2p,
    const _Float16* __restrict__ Wc1p,
    float* __restrict__ out_sdf, float* __restrict__ ws_a,
    float* __restrict__ ws_rgb, float* __restrict__ ws_nrm,
    int Nsamp)
{
    __shared__ SMemK2 sm;
    const int tid = threadIdx.x;
    const int lane = tid & 63;
    const int w = tid >> 6;          // 0..7
    const int n0 = blockIdx.x * TILE;

    // ---- P0: points, dirs, split Wg2[:,0]
    if (tid < 256) {
        float v = Wg2[tid * 16];
        splitst(v, &sm.w2h[tid], &sm.w2l[tid]);
    }
    if (tid < TILE) {
        int n = n0 + tid; if (n >= Nsamp) n = Nsamp - 1;
        int ri = ray_idx[n];
        float dx = rays_d[ri * 3 + 0], dy = rays_d[ri * 3 + 1], dz = rays_d[ri * 3 + 2];
        float inv = 1.f / (sqrtf(dx * dx + dy * dy + dz * dz) + 1e-10f);
        dx *= inv; dy *= inv; dz *= inv;
        float mid = t_starts[n] + 0.0025f;
        sm.dirs[tid * 4 + 0] = dx; sm.dirs[tid * 4 + 1] = dy; sm.dirs[tid * 4 + 2] = dz;
        float px = rays_o[ri * 3 + 0] + dx * mid;
        float py = rays_o[ri * 3 + 1] + dy * mid;
        float pz = rays_o[ri * 3 + 2] + dz * mid;
        sm.pts[tid * 4 + 0] = px; sm.pts[tid * 4 + 1] = py; sm.pts[tid * 4 + 2] = pz;
        splitst(px, &sm.ench[tid * LDE + 0], &sm.encl[tid * LDE + 0]);
        splitst(py, &sm.ench[tid * LDE + 1], &sm.encl[tid * LDE + 1]);
        splitst(pz, &sm.ench[tid * LDE + 2], &sm.encl[tid * LDE + 2]);
    }
    __syncthreads();

    // ---- P1: positional encoding (split at write) + zero pad cols 39..63
    for (int i = tid; i < TILE * 36; i += NTHREADS) {
        int s = i & (TILE - 1);
        int e = i >> 5;                    // 0..35
        int f = e / 6, r = e - f * 6;
        float freq = PI_F * (float)(1 << f);
        int d = (r < 3) ? r : r - 3;
        float x = sm.pts[s * 4 + d];
        float v = (r < 3) ? sinf(freq * x) : cosf(freq * x);
        splitst(v, &sm.ench[s * LDE + 3 + e], &sm.encl[s * LDE + 3 + e]);
    }
    for (int i = tid; i < TILE * 25; i += NTHREADS) {
        int s = i / 25, c = 39 + (i - s * 25);
        sm.ench[s * LDE + c] = (_Float16)0.f;
        sm.encl[s * LDE + c] = (_Float16)0.f;
    }
    __syncthreads();

    // ---- P2: h0 = relu(enc @ Wg0 + bg0) -> act0 planes   (K pad 64)
    gemm32<4, true, true, false, false>(sm.ench, sm.encl, LDE, nullptr, nullptr,
                                        Wg0p, bg0, sm.a0h, sm.a0l, LDP, lane, w);
    __syncthreads();

    // ---- P3: h1 = relu(h0 @ Wg1 + bg1) -> act1 planes
    gemm32<16, true, true, false, false>(sm.a0h, sm.a0l, LDP, nullptr, nullptr,
                                         Wg1p, bg1, sm.a1h, sm.a1l, LDP, lane, w);
    __syncthreads();

    // ---- P4: feats = h1 @ Wg2 + bg2 (waves 0,1; 16x16 path); sdf out
    if (w < 2) {
        f32x4 acc = (f32x4){0.f, 0.f, 0.f, 0.f};
        const int m = w * 16 + (lane & 15);
        const int q8 = (lane >> 4) * 8;
        const _Float16* ahb = sm.a1h + m * LDP + q8;
        const _Float16* alb = sm.a1l + m * LDP + q8;
        const _Float16* bbase = Wg2p + lane * 16;
#pragma unroll
        for (int kit = 0; kit < 8; ++kit) {
            half8 ah = *(const half8*)(ahb + kit * 32);
            half8 al = *(const half8*)(alb + kit * 32);
            const _Float16* bp = bbase + kit * 1024;
            half8 bh = *(const half8*)bp;
            half8 bl = *(const half8*)(bp + 8);
            acc = __builtin_amdgcn_mfma_f32_16x16x32_f16(al, bh, acc, 0, 0, 0);
            acc = __builtin_amdgcn_mfma_f32_16x16x32_f16(ah, bl, acc, 0, 0, 0);
            acc = __builtin_amdgcn_mfma_f32_16x16x32_f16(ah, bh, acc, 0, 0, 0);
        }
        int col = lane & 15, q = lane >> 4;
        float bs = bg2[col];
#pragma unroll
        for (int r = 0; r < 4; ++r) {
            int s = w * 16 + q * 4 + r;
            float vv = acc[r] + bs;
            sm.feats[s * 16 + col] = vv;
            if (col == 0) { int n = n0 + s; if (n < Nsamp) out_sdf[n] = vv; }
        }
    }
    // no barrier: P6 reads act1/w2 planes (stable); each wave's P6 output tile
    // (rows 0..31, cols w*32..) only masks against h0 cells it wrote in P2.

    // ---- P6: g1 = ((h1>0)*wg2c0) @ Wg1T, out-gated by (h0>0) -> act0 planes
    gemm32<16, false, false, true, true>(sm.a1h, sm.a1l, LDP, sm.w2h, sm.w2l,
                                         Wg1Tp, nullptr, sm.a0h, sm.a0l, LDP, lane, w);
    __syncthreads();

    // ---- P7: g0 = g1 @ Wg0T -> act1 planes cols 0..63 (39 valid)
    gemm16<8, 1>(sm.a0h, sm.a0l, LDP, Wg0Tp,
                 sm.a1h, sm.a1l, LDP, lane, w & 1, w >> 1);
    __syncthreads();

    // ---- P7b: grad through encoding, normal, alpha
    if (tid < TILE) {
        int s = tid;
        float g[3];
#pragma unroll
        for (int d = 0; d < 3; ++d)
            g[d] = (float)sm.a1h[s * LDP + d] + (float)sm.a1l[s * LDP + d];
#pragma unroll
        for (int f = 0; f < 6; ++f) {
            float freq = PI_F * (float)(1 << f);
#pragma unroll
            for (int d = 0; d < 3; ++d) {
                int cs = 3 + f * 6 + d, cc = cs + 3;
                float gs = (float)sm.a1h[s * LDP + cs] + (float)sm.a1l[s * LDP + cs];
                float gc = (float)sm.a1h[s * LDP + cc] + (float)sm.a1l[s * LDP + cc];
                float sv = (float)sm.ench[s * LDE + cs] + (float)sm.encl[s * LDE + cs];
                float cv = (float)sm.ench[s * LDE + cc] + (float)sm.encl[s * LDE + cc];
                g[d] += freq * (gs * cv - gc * sv);
            }
        }
        float gl = sqrtf(g[0] * g[0] + g[1] * g[1] + g[2] * g[2]);
        float invl = 1.f / (gl + 1e-10f);
        float nx = g[0] * invl, ny = g[1] * invl, nz = g[2] * invl;
        sm.nrm[s * 4 + 0] = nx; sm.nrm[s * 4 + 1] = ny; sm.nrm[s * 4 + 2] = nz;
        float dx = sm.dirs[s * 4 + 0], dy = sm.dirs[s * 4 + 1], dz = sm.dirs[s * 4 + 2];
        float dsdt = fminf(g[0] * dx + g[1] * dy + g[2] * dz, 0.f);
        float sdf = sm.feats[s * 16 + 0];
        float inv_s = __expf(s_var[0]);
        inv_s = fminf(fmaxf(inv_s, 1e-6f), 1e6f);
        float cdf = 1.f / (1.f + __expf(-inv_s * sdf));
        float rho = fmaxf(inv_s * (cdf - 1.f) * dsdt, 0.f);
        float alpha = 1.f - __expf(-rho * 0.005f);
        float a = fminf(fmaxf(alpha, 0.f), 1.f - 1e-7f);
        int n = n0 + s;
        if (n < Nsamp) {
            ws_a[n] = a;
            ws_nrm[n * 3 + 0] = nx; ws_nrm[n * 3 + 1] = ny; ws_nrm[n * 3 + 2] = nz;
        }
    }
    __syncthreads();

    // ---- P8a: cin = [dirs(3), feats(16), points(3), normal(3), 0pad..31]
    _Float16* cinh = sm.a0h;   // overlay (g1 dead)
    _Float16* cinl = sm.a0l;
    for (int i = tid; i < TILE * 32; i += NTHREADS) {
        int s = i >> 5, c = i & 31;
        float v = 0.f;
        if      (c < 3)  v = sm.dirs[s * 4 + c];
        else if (c < 19) v = sm.feats[s * 16 + (c - 3)];
        else if (c < 22) v = sm.pts[s * 4 + (c - 19)];
        else if (c < 25) v = sm.nrm[s * 4 + (c - 22)];
        splitst(v, &cinh[s * LDCIN + c], &cinl[s * LDCIN + c]);
    }
    __syncthreads();

    // ---- P8: hc = relu(cin @ Wc0 + bc0) -> act1 planes  (K pad 32)
    gemm32<2, true, true, false, false>(cinh, cinl, LDCIN, nullptr, nullptr,
                                        Wc0p, bc0, sm.a1h, sm.a1l, LDP, lane, w);
    __syncthreads();

    // ---- P9: rgb = sigmoid(hc @ Wc1 + bc1) (waves 0,1; 16x16 path)
    if (w < 2) {
        f32x4 acc = (f32x4){0.f, 0.f, 0.f, 0.f};
        const int m = w * 16 + (lane & 15);
        const int q8 = (lane >> 4) * 8;
        const _Float16* ahb = sm.a1h + m * LDP + q8;
        const _Float16* alb = sm.a1l + m * LDP + q8;
        const _Float16* bbase = Wc1p + lane * 16;
#pragma unroll
        for (int kit = 0; kit < 8; ++kit) {
            half8 ah = *(const half8*)(ahb + kit * 32);
            half8 al = *(const half8*)(alb + kit * 32);
            const _Float16* bp = bbase + kit * 1024;
            half8 bh = *(const half8*)bp;
            half8 bl = *(const half8*)(bp + 8);
            acc = __builtin_amdgcn_mfma_f32_16x16x32_f16(al, bh, acc, 0, 0, 0);
            acc = __builtin_amdgcn_mfma_f32_16x16x32_f16(ah, bl, acc, 0, 0, 0);
            acc = __builtin_amdgcn_mfma_f32_16x16x32_f16(ah, bh, acc, 0, 0, 0);
        }
        int col = lane & 15, q = lane >> 4;
        if (col < 3) {
#pragma unroll
            for (int r = 0; r < 4; ++r) {
                int s = w * 16 + q * 4 + r;
                float rgb = 1.f / (1.f + __expf(-(acc[r] + bc1[col])));
                int n = n0 + s;
                if (n < Nsamp) ws_rgb[n * 3 + col] = rgb;
            }
        }
    }
}

// ---------------- K3: per-ray compositing ----------------------------------
__global__ void k3_composite(
    const int* __restrict__ ray_idx, const float* __restrict__ t_starts,
    const float* __restrict__ ws_a, const float* __restrict__ ws_rgb,
    const float* __restrict__ ws_nrm,
    float* __restrict__ out_pc, float* __restrict__ out_pn,
    float* __restrict__ out_op, float* __restrict__ out_dp,
    float* __restrict__ out_w, int n_rays, int Nsamp)
{
    int r = blockIdx.x * blockDim.x + threadIdx.x;
    if (r >= n_rays) return;
    int lo = 0, hi = Nsamp;
    while (lo < hi) { int m = (lo + hi) >> 1; if (ray_idx[m] < r) lo = m + 1; else hi = m; }
    int start = lo;
    hi = Nsamp;
    while (lo < hi) { int m = (lo + hi) >> 1; if (ray_idx[m] < r + 1) lo = m + 1; else hi = m; }
    int end = lo;

    float T = 1.f, aco = 0.f, acd = 0.f;
    float c0 = 0.f, c1 = 0.f, c2 = 0.f, nx = 0.f, ny = 0.f, nz = 0.f;
    for (int n = start; n < end; ++n) {
        float a = ws_a[n];
        float wgt = a * T;
        T *= (1.f - a);
        out_w[n] = wgt;
        float mid = t_starts[n] + 0.0025f;
        aco += wgt; acd += wgt * mid;
        c0 += wgt * ws_rgb[n * 3 + 0];
        c1 += wgt * ws_rgb[n * 3 + 1];
        c2 += wgt * ws_rgb[n * 3 + 2];
        nx += wgt * ws_nrm[n * 3 + 0];
        ny += wgt * ws_nrm[n * 3 + 1];
        nz += wgt * ws_nrm[n * 3 + 2];
    }
    out_op[r] = aco;
    out_dp[r] = acd;
    out_pc[r * 3 + 0] = c0; out_pc[r * 3 + 1] = c1; out_pc[r * 3 + 2] = c2;
    float nl = sqrtf(nx * nx + ny * ny + nz * nz);
    float inv = 1.f / (nl + 1e-10f);
    out_pn[r * 3 + 0] = nx * inv; out_pn[r * 3 + 1] = ny * inv; out_pn[r * 3 + 2] = nz * inv;
}

// ---------------- K4: random_sdfs ------------------------------------------
__global__ __launch_bounds__(256) void k4_random(
    const float* __restrict__ pts,
    const float* __restrict__ Wg0, const float* __restrict__ bg0,
    const float* __restrict__ Wg1, const float* __restrict__ bg1,
    const float* __restrict__ Wg2, const float* __restrict__ bg2,
    float* __restrict__ out_rs, int n_rand)
{
    __shared__ float enc[40];
    __shared__ float h[256];
    __shared__ float red[256];
    int b = blockIdx.x;
    if (b >= n_rand) return;
    int tid = threadIdx.x;
    if (tid < 39) {
        int c = tid;
        float v;
        if (c < 3) v = pts[b * 3 + c];
        else {
            int e = c - 3, f = e / 6, r = e - f * 6;
            float freq = PI_F * (float)(1 << f);
            int d = (r < 3) ? r : r - 3;
            float x = pts[b * 3 + d];
            v = (r < 3) ? sinf(freq * x) : cosf(freq * x);
        }
        enc[c] = v;
    }
    __syncthreads();
    {
        float z = bg0[tid];
        for (int m = 0; m < 39; ++m) z += enc[m] * Wg0[m * 256 + tid];
        h[tid] = fmaxf(z, 0.f);
    }
    __syncthreads();
    {
        float z = bg1[tid];
        for (int k = 0; k < 256; ++k) z += h[k] * Wg1[k * 256 + tid];
        float h1 = fmaxf(z, 0.f);
        red[tid] = h1 * Wg2[tid * 16];   // Wg2[:,0]
    }
    __syncthreads();
    for (int off = 128; off > 0; off >>= 1) {
        if (tid < off) red[tid] += red[tid + off];
        __syncthreads();
    }
    if (tid == 0) out_rs[b] = red[0] + bg2[0];
}

extern "C" void kernel_launch(void* const* d_in, const int* in_sizes, int n_in,
                              void* d_out, int out_size, void* d_ws, size_t ws_size,
                              hipStream_t stream)
{
    const float* rays_o   = (const float*)d_in[0];
    const float* rays_d   = (const float*)d_in[1];
    const int*   ray_idx  = (const int*)  d_in[2];
    const float* t_starts = (const float*)d_in[3];
    const float* rpts     = (const float*)d_in[4];
    const float* s_var    = (const float*)d_in[5];
    const float* Wg0 = (const float*)d_in[6];  const float* bg0 = (const float*)d_in[7];
    const float* Wg1 = (const float*)d_in[8];  const float* bg1 = (const float*)d_in[9];
    const float* Wg2 = (const float*)d_in[10]; const float* bg2 = (const float*)d_in[11];
    const float* Wc0 = (const float*)d_in[12]; const float* bc0 = (const float*)d_in[13];
    const float* Wc1 = (const float*)d_in[14]; const float* bc1 = (const float*)d_in[15];

    const int n_rays = in_sizes[0] / 3;
    const int Ns     = in_sizes[2];
    const int n_rand = in_sizes[4] / 3;

    float* out  = (float*)d_out;
    float* o_pc = out;
    float* o_pn = out + (size_t)3 * n_rays;
    float* o_op = out + (size_t)6 * n_rays;
    float* o_dp = out + (size_t)7 * n_rays;
    float* o_w  = out + (size_t)8 * n_rays;
    float* o_sdf = o_w + Ns;
    float* o_rs  = o_sdf + Ns;

    // ws: packed f16 weights first, then float scratch
    _Float16* hptr  = (_Float16*)d_ws;
    _Float16* Wg0p  = hptr;                 // 32768 halves
    _Float16* Wg1p  = Wg0p  + 32768;        // 131072
    _Float16* Wg1Tp = Wg1p  + 131072;       // 131072
    _Float16* Wg0Tp = Wg1Tp + 131072;       // 32768
    _Float16* Wc0p  = Wg0Tp + 32768;        // 16384
    _Float16* Wg2p  = Wc0p  + 16384;        // 8192
    _Float16* Wc1p  = Wg2p  + 8192;         // 8192  -> total 360448 halves
    float* fbase  = (float*)(hptr + 360448);
    float* ws_a   = fbase;
    float* ws_rgb = ws_a + Ns;
    float* ws_nrm = ws_rgb + (size_t)3 * Ns;

    hipLaunchKernelGGL(k0_pack, dim3(704), dim3(256), 0, stream,
                       Wg0, Wg1, Wg2, Wc0, Wc1,
                       Wg0p, Wg1p, Wg1Tp, Wg0Tp, Wc0p, Wg2p, Wc1p);
    hipLaunchKernelGGL(k2_mlp, dim3((Ns + TILE - 1) / TILE), dim3(NTHREADS), 0, stream,
                       rays_o, rays_d, ray_idx, t_starts, s_var,
                       bg0, bg1, Wg2, bg2, bc0, bc1,
                       Wg0p, Wg1p, Wg1Tp, Wg0Tp, Wc0p, Wg2p, Wc1p,
                       o_sdf, ws_a, ws_rgb, ws_nrm, Ns);
    hipLaunchKernelGGL(k4_random, dim3(n_rand), dim3(256), 0, stream,
                       rpts, Wg0, bg0, Wg1, bg1, Wg2, bg2, o_rs, n_rand);
    hipLaunchKernelGGL(k3_composite, dim3((n_rays + 255) / 256), dim3(256), 0, stream,
                       ray_idx, t_starts, ws_a, ws_rgb, ws_nrm,
                       o_pc, o_pn, o_op, o_dp, o_w, n_rays, Ns);
}

// Round 2
// 774.935 us; speedup vs baseline: 1.2468x; 1.2106x over previous
//
#include <hip/hip_runtime.h>
#include <math.h>

// ---------------------------------------------------------------------------
// NeuS-style fused renderer, R5.
//  - Split f16 hi/lo activation planes in LDS (split once at producer).
//  - N=256 GEMMs use v_mfma_f32_32x32x16_f16.
//  - R5: depth-2 rotating prefetch of B (global/L2) and A (LDS) in all GEMM
//    loops (VGPR 56 showed R4 issued loads just-in-time -> per-kit stalls).
//  - R5: P6 uses Wg1T pre-scaled by Wg2[:,0] at pack time; A is an exact 0/1
//    f16 mask (2 ops/elem, lo-plane = 0) -> 2 MFMAs/kit instead of 3.
//  - R5: s_setprio(1) around MFMA clusters (role-diverse waves, 2 blocks/CU).
// ---------------------------------------------------------------------------

#define TILE 32
#define NTHREADS 512
#define LDP 264     // act plane stride (halves)
#define LDE 72      // enc plane stride (halves)
#define LDCIN 40    // cin plane stride (halves)
#define PI_F 3.14159265358979323846f

typedef _Float16 half8 __attribute__((ext_vector_type(8)));
typedef float f32x4 __attribute__((ext_vector_type(4)));
typedef float f32x16 __attribute__((ext_vector_type(16)));

struct alignas(16) SMemK2 {
    _Float16 a0h[TILE * LDP];   // h0 -> g1 -> cin(overlay)
    _Float16 a0l[TILE * LDP];
    _Float16 a1h[TILE * LDP];   // h1 -> g0(cols 0..63) -> hc
    _Float16 a1l[TILE * LDP];
    _Float16 ench[TILE * LDE];  // [x(3), sin/cos(36), 0-pad..63]
    _Float16 encl[TILE * LDE];
    float feats[TILE * 16];
    float pts [TILE * 4];
    float dirs[TILE * 4];
    float nrm [TILE * 4];
};  // 80384 B -> 2 blocks/CU

__device__ __forceinline__ void splitst(float v, _Float16* ph, _Float16* pl) {
    _Float16 h = (_Float16)v;
    *ph = h;
    *pl = (_Float16)(v - (float)h);
}

__device__ __forceinline__ f32x16 zero16() {
    f32x16 z;
#pragma unroll
    for (int i = 0; i < 16; ++i) z[i] = 0.f;
    return z;
}

// 32x32 output tile per wave, K = KITERS*16, cols nt*32..+32.
// A: split planes in LDS. B packed: hi8|lo8 per (nt,kit,lane).
// AMASK: A := (h1>0) ? 1 : 0 exactly (B carries w2c0 scaling); lo-plane = 0,
//        so only 2 MFMAs per kit.
// CMASK: epilogue gates by old C hi-plane sign (h0>0).
template<int KITERS, bool BIAS, bool RELU, bool AMASK, bool CMASK>
__device__ __forceinline__ void gemm32(
    const _Float16* Ah, const _Float16* Al, const int lda,
    const _Float16* __restrict__ Bp, const float* __restrict__ bias,
    _Float16* Ch, _Float16* Cl, const int ldc,
    const int lane, const int nt)
{
    f32x16 acc0 = zero16(), acc1 = zero16();
    const int row  = lane & 31;
    const int koff = (lane >> 5) * 8;
    const _Float16* ahb = Ah + row * lda + koff;
    const _Float16* alb = Al + row * lda + koff;
    const _Float16* bbase = Bp + ((size_t)nt * KITERS * 64 + lane) * 16;

    half8 bh[2], bl[2], ax[2], ay[2];
    bh[0] = *(const half8*)bbase;
    bl[0] = *(const half8*)(bbase + 8);
    ax[0] = *(const half8*)ahb;
    if (!AMASK) ay[0] = *(const half8*)alb;

#pragma unroll
    for (int kit = 0; kit < KITERS; ++kit) {
        const int cur = kit & 1, nxt = cur ^ 1;
        if (kit + 1 < KITERS) {
            const _Float16* bp = bbase + (size_t)(kit + 1) * 1024;
            bh[nxt] = *(const half8*)bp;
            bl[nxt] = *(const half8*)(bp + 8);
            ax[nxt] = *(const half8*)(ahb + (kit + 1) * 16);
            if (!AMASK) ay[nxt] = *(const half8*)(alb + (kit + 1) * 16);
        }
        f32x16& acc = (kit & 1) ? acc1 : acc0;
        if (AMASK) {
            // exact 0/1 mask: relu clamps positives to >=1e-4, so f16 h>0
            // iff h != 0; min(h*16384, 1) == 1 for h>=1e-4, == 0 for h==0.
            half8 m;
#pragma unroll
            for (int j = 0; j < 8; ++j) {
                _Float16 t = ax[cur][j] * (_Float16)16384.f;
                m[j] = (t < (_Float16)1.f) ? t : (_Float16)1.f;
            }
            __builtin_amdgcn_s_setprio(1);
            acc = __builtin_amdgcn_mfma_f32_32x32x16_f16(m, bh[cur], acc, 0, 0, 0);
            acc = __builtin_amdgcn_mfma_f32_32x32x16_f16(m, bl[cur], acc, 0, 0, 0);
            __builtin_amdgcn_s_setprio(0);
        } else {
            __builtin_amdgcn_s_setprio(1);
            acc = __builtin_amdgcn_mfma_f32_32x32x16_f16(ay[cur], bh[cur], acc, 0, 0, 0);
            acc = __builtin_amdgcn_mfma_f32_32x32x16_f16(ax[cur], bl[cur], acc, 0, 0, 0);
            acc = __builtin_amdgcn_mfma_f32_32x32x16_f16(ax[cur], bh[cur], acc, 0, 0, 0);
            __builtin_amdgcn_s_setprio(0);
        }
    }
    const int col = lane & 31;
    const int rb  = (lane >> 5) * 4;
    const int jc  = nt * 32 + col;
    const float bs = BIAS ? bias[jc] : 0.f;
#pragma unroll
    for (int r = 0; r < 16; ++r) {
        const int srow = (r & 3) + 8 * (r >> 2) + rb;
        float v = acc0[r] + acc1[r] + bs;
        if (RELU) v = (v > 0.f) ? fmaxf(v, 1e-4f) : 0.f;
        if (CMASK) { if (!((float)Ch[srow * ldc + jc] > 0.f)) v = 0.f; }
        _Float16 h = (_Float16)v;
        Ch[srow * ldc + jc] = h;
        Cl[srow * ldc + jc] = (_Float16)(v - (float)h);
    }
}

// 16x16 path (P7): rows mt*16..+16, cols (ntbase..+NTPW)*16, split-plane A.
template<int KITERS, int NTPW>
__device__ __forceinline__ void gemm16(
    const _Float16* Ah, const _Float16* Al, const int lda,
    const _Float16* __restrict__ Bp,
    _Float16* Ch, _Float16* Cl, const int ldc,
    const int lane, const int mt, const int ntbase)
{
    f32x4 acc[NTPW];
#pragma unroll
    for (int t = 0; t < NTPW; ++t) acc[t] = (f32x4){0.f, 0.f, 0.f, 0.f};
    const int m  = mt * 16 + (lane & 15);
    const int q8 = (lane >> 4) * 8;
    const _Float16* ahb = Ah + m * lda + q8;
    const _Float16* alb = Al + m * lda + q8;
    const _Float16* bbase = Bp + ((size_t)ntbase * KITERS * 64 + lane) * 16;

    half8 ax[2], ay[2], bh[2][NTPW], bl[2][NTPW];
    ax[0] = *(const half8*)ahb;
    ay[0] = *(const half8*)alb;
#pragma unroll
    for (int t = 0; t < NTPW; ++t) {
        const _Float16* bt = bbase + (size_t)t * KITERS * 1024;
        bh[0][t] = *(const half8*)bt;
        bl[0][t] = *(const half8*)(bt + 8);
    }
#pragma unroll
    for (int kit = 0; kit < KITERS; ++kit) {
        const int cur = kit & 1, nxt = cur ^ 1;
        if (kit + 1 < KITERS) {
            ax[nxt] = *(const half8*)(ahb + (kit + 1) * 32);
            ay[nxt] = *(const half8*)(alb + (kit + 1) * 32);
            const _Float16* bp = bbase + (size_t)(kit + 1) * 1024;
#pragma unroll
            for (int t = 0; t < NTPW; ++t) {
                const _Float16* bt = bp + (size_t)t * KITERS * 1024;
                bh[nxt][t] = *(const half8*)bt;
                bl[nxt][t] = *(const half8*)(bt + 8);
            }
        }
        __builtin_amdgcn_s_setprio(1);
#pragma unroll
        for (int t = 0; t < NTPW; ++t) {
            acc[t] = __builtin_amdgcn_mfma_f32_16x16x32_f16(ay[cur], bh[cur][t], acc[t], 0, 0, 0);
            acc[t] = __builtin_amdgcn_mfma_f32_16x16x32_f16(ax[cur], bl[cur][t], acc[t], 0, 0, 0);
            acc[t] = __builtin_amdgcn_mfma_f32_16x16x32_f16(ax[cur], bh[cur][t], acc[t], 0, 0, 0);
        }
        __builtin_amdgcn_s_setprio(0);
    }
    const int col = lane & 15, q = lane >> 4;
#pragma unroll
    for (int t = 0; t < NTPW; ++t) {
        const int j = (ntbase + t) * 16 + col;
#pragma unroll
        for (int r = 0; r < 4; ++r) {
            const int s = mt * 16 + q * 4 + r;
            float v = acc[t][r];
            _Float16 h = (_Float16)v;
            Ch[s * ldc + j] = h;
            Cl[s * ldc + j] = (_Float16)(v - (float)h);
        }
    }
}

// ---------------- K0: pack weights to hi|lo B-fragment layouts --------------
// modes 0,1,2,4 -> 32x32x16 layout; modes 3,5,6 -> 16x16x32 layout.
// mode 2 (Wg1T) is pre-scaled by Wg2[:,0] so P6's A can be a pure 0/1 mask.
__global__ __launch_bounds__(256) void k0_pack(
    const float* __restrict__ Wg0, const float* __restrict__ Wg1,
    const float* __restrict__ Wg2, const float* __restrict__ Wc0,
    const float* __restrict__ Wc1,
    _Float16* __restrict__ Wg0p, _Float16* __restrict__ Wg1p,
    _Float16* __restrict__ Wg1Tp, _Float16* __restrict__ Wg0Tp,
    _Float16* __restrict__ Wc0p, _Float16* __restrict__ Wg2p,
    _Float16* __restrict__ Wc1p)
{
    int gid = blockIdx.x * 256 + threadIdx.x;
    if (gid >= 180224) return;
    int idx, kiters, mode;
    _Float16* dst;
    if      (gid <  16384) { idx = gid;          kiters = 4;  dst = Wg0p;  mode = 0; }
    else if (gid <  81920) { idx = gid -  16384; kiters = 16; dst = Wg1p;  mode = 1; }
    else if (gid < 147456) { idx = gid -  81920; kiters = 16; dst = Wg1Tp; mode = 2; }
    else if (gid < 163840) { idx = gid - 147456; kiters = 8;  dst = Wg0Tp; mode = 3; }
    else if (gid < 172032) { idx = gid - 163840; kiters = 2;  dst = Wc0p;  mode = 4; }
    else if (gid < 176128) { idx = gid - 172032; kiters = 8;  dst = Wg2p;  mode = 5; }
    else                   { idx = gid - 176128; kiters = 8;  dst = Wc1p;  mode = 6; }
    const bool p32 = (mode == 0 || mode == 1 || mode == 2 || mode == 4);
    int j = idx & 7, lane = (idx >> 3) & 63, rest = idx >> 9;
    int kit = rest % kiters, nt = rest / kiters;
    int k, n;
    if (p32) { k = kit * 16 + ((lane >> 5) << 3) + j; n = (nt << 5) + (lane & 31); }
    else     { k = kit * 32 + ((lane >> 4) << 3) + j; n = (nt << 4) + (lane & 15); }
    float val = 0.f;
    switch (mode) {
        case 0: val = (k < 39) ? Wg0[k * 256 + n] : 0.f; break;
        case 1: val = Wg1[k * 256 + n]; break;
        case 2: val = Wg1[n * 256 + k] * Wg2[k * 16]; break;    // Wg1^T * w2c0
        case 3: val = (n < 39) ? Wg0[n * 256 + k] : 0.f; break; // Wg0^T
        case 4: val = (k < 25) ? Wc0[k * 256 + n] : 0.f; break;
        case 5: val = Wg2[k * 16 + n]; break;
        case 6: val = (n < 3) ? Wc1[k * 3 + n] : 0.f; break;
    }
    _Float16 h = (_Float16)val;
    _Float16 l = (_Float16)(val - (float)h);
    int off = ((nt * kiters + kit) * 64 + lane) * 16 + j;
    dst[off] = h;
    dst[off + 8] = l;
}

// ---------------- K2: the fused MLP (8 waves) ------------------------------
__global__ __launch_bounds__(512, 4) void k2_mlp(
    const float* __restrict__ rays_o, const float* __restrict__ rays_d,
    const int*   __restrict__ ray_idx, const float* __restrict__ t_starts,
    const float* __restrict__ s_var,
    const float* __restrict__ bg0, const float* __restrict__ bg1,
    const float* __restrict__ bg2,
    const float* __restrict__ bc0, const float* __restrict__ bc1,
    const _Float16* __restrict__ Wg0p, const _Float16* __restrict__ Wg1p,
    const _Float16* __restrict__ Wg1Tp, const _Float16* __restrict__ Wg0Tp,
    const _Float16* __restrict__ Wc0p, const _Float16* __restrict__ Wg2p,
    const _Float16* __restrict__ Wc1p,
    float* __restrict__ out_sdf, float* __restrict__ ws_a,
    float* __restrict__ ws_rgb, float* __restrict__ ws_nrm,
    int Nsamp)
{
    __shared__ SMemK2 sm;
    const int tid = threadIdx.x;
    const int lane = tid & 63;
    const int w = tid >> 6;          // 0..7
    const int n0 = blockIdx.x * TILE;

    // ---- P0: points, dirs
    if (tid < TILE) {
        int n = n0 + tid; if (n >= Nsamp) n = Nsamp - 1;
        int ri = ray_idx[n];
        float dx = rays_d[ri * 3 + 0], dy = rays_d[ri * 3 + 1], dz = rays_d[ri * 3 + 2];
        float inv = 1.f / (sqrtf(dx * dx + dy * dy + dz * dz) + 1e-10f);
        dx *= inv; dy *= inv; dz *= inv;
        float mid = t_starts[n] + 0.0025f;
        sm.dirs[tid * 4 + 0] = dx; sm.dirs[tid * 4 + 1] = dy; sm.dirs[tid * 4 + 2] = dz;
        float px = rays_o[ri * 3 + 0] + dx * mid;
        float py = rays_o[ri * 3 + 1] + dy * mid;
        float pz = rays_o[ri * 3 + 2] + dz * mid;
        sm.pts[tid * 4 + 0] = px; sm.pts[tid * 4 + 1] = py; sm.pts[tid * 4 + 2] = pz;
        splitst(px, &sm.ench[tid * LDE + 0], &sm.encl[tid * LDE + 0]);
        splitst(py, &sm.ench[tid * LDE + 1], &sm.encl[tid * LDE + 1]);
        splitst(pz, &sm.ench[tid * LDE + 2], &sm.encl[tid * LDE + 2]);
    }
    __syncthreads();

    // ---- P1: positional encoding (split at write) + zero pad cols 39..63
    for (int i = tid; i < TILE * 36; i += NTHREADS) {
        int s = i & (TILE - 1);
        int e = i >> 5;                    // 0..35
        int f = e / 6, r = e - f * 6;
        float freq = PI_F * (float)(1 << f);
        int d = (r < 3) ? r : r - 3;
        float x = sm.pts[s * 4 + d];
        float v = (r < 3) ? sinf(freq * x) : cosf(freq * x);
        splitst(v, &sm.ench[s * LDE + 3 + e], &sm.encl[s * LDE + 3 + e]);
    }
    for (int i = tid; i < TILE * 25; i += NTHREADS) {
        int s = i / 25, c = 39 + (i - s * 25);
        sm.ench[s * LDE + c] = (_Float16)0.f;
        sm.encl[s * LDE + c] = (_Float16)0.f;
    }
    __syncthreads();

    // ---- P2: h0 = relu(enc @ Wg0 + bg0) -> act0 planes   (K pad 64)
    gemm32<4, true, true, false, false>(sm.ench, sm.encl, LDE,
                                        Wg0p, bg0, sm.a0h, sm.a0l, LDP, lane, w);
    __syncthreads();

    // ---- P3: h1 = relu(h0 @ Wg1 + bg1) -> act1 planes
    gemm32<16, true, true, false, false>(sm.a0h, sm.a0l, LDP,
                                         Wg1p, bg1, sm.a1h, sm.a1l, LDP, lane, w);
    __syncthreads();

    // ---- P4: feats = h1 @ Wg2 + bg2 (waves 0,1; 16x16 path); sdf out
    if (w < 2) {
        f32x4 acc = (f32x4){0.f, 0.f, 0.f, 0.f};
        const int m = w * 16 + (lane & 15);
        const int q8 = (lane >> 4) * 8;
        const _Float16* ahb = sm.a1h + m * LDP + q8;
        const _Float16* alb = sm.a1l + m * LDP + q8;
        const _Float16* bbase = Wg2p + lane * 16;
        half8 ax[2], ay[2], bh[2], bl[2];
        ax[0] = *(const half8*)ahb;
        ay[0] = *(const half8*)alb;
        bh[0] = *(const half8*)bbase;
        bl[0] = *(const half8*)(bbase + 8);
#pragma unroll
        for (int kit = 0; kit < 8; ++kit) {
            const int cur = kit & 1, nxt = cur ^ 1;
            if (kit + 1 < 8) {
                ax[nxt] = *(const half8*)(ahb + (kit + 1) * 32);
                ay[nxt] = *(const half8*)(alb + (kit + 1) * 32);
                const _Float16* bp = bbase + (kit + 1) * 1024;
                bh[nxt] = *(const half8*)bp;
                bl[nxt] = *(const half8*)(bp + 8);
            }
            __builtin_amdgcn_s_setprio(1);
            acc = __builtin_amdgcn_mfma_f32_16x16x32_f16(ay[cur], bh[cur], acc, 0, 0, 0);
            acc = __builtin_amdgcn_mfma_f32_16x16x32_f16(ax[cur], bl[cur], acc, 0, 0, 0);
            acc = __builtin_amdgcn_mfma_f32_16x16x32_f16(ax[cur], bh[cur], acc, 0, 0, 0);
            __builtin_amdgcn_s_setprio(0);
        }
        int col = lane & 15, q = lane >> 4;
        float bs = bg2[col];
#pragma unroll
        for (int r = 0; r < 4; ++r) {
            int s = w * 16 + q * 4 + r;
            float vv = acc[r] + bs;
            sm.feats[s * 16 + col] = vv;
            if (col == 0) { int n = n0 + s; if (n < Nsamp) out_sdf[n] = vv; }
        }
    }
    // no barrier: P6 reads act1 planes (stable); each wave's P6 output tile
    // only masks against h0 cells it wrote in P2.

    // ---- P6: g1 = mask(h1) @ (Wg1T*w2c0), out-gated by (h0>0) -> act0 planes
    gemm32<16, false, false, true, true>(sm.a1h, sm.a1l, LDP,
                                         Wg1Tp, nullptr, sm.a0h, sm.a0l, LDP, lane, w);
    __syncthreads();

    // ---- P7: g0 = g1 @ Wg0T -> act1 planes cols 0..63 (39 valid)
    gemm16<8, 1>(sm.a0h, sm.a0l, LDP, Wg0Tp,
                 sm.a1h, sm.a1l, LDP, lane, w & 1, w >> 1);
    __syncthreads();

    // ---- P7b: grad through encoding, normal, alpha
    if (tid < TILE) {
        int s = tid;
        float g[3];
#pragma unroll
        for (int d = 0; d < 3; ++d)
            g[d] = (float)sm.a1h[s * LDP + d] + (float)sm.a1l[s * LDP + d];
#pragma unroll
        for (int f = 0; f < 6; ++f) {
            float freq = PI_F * (float)(1 << f);
#pragma unroll
            for (int d = 0; d < 3; ++d) {
                int cs = 3 + f * 6 + d, cc = cs + 3;
                float gs = (float)sm.a1h[s * LDP + cs] + (float)sm.a1l[s * LDP + cs];
                float gc = (float)sm.a1h[s * LDP + cc] + (float)sm.a1l[s * LDP + cc];
                float sv = (float)sm.ench[s * LDE + cs] + (float)sm.encl[s * LDE + cs];
                float cv = (float)sm.ench[s * LDE + cc] + (float)sm.encl[s * LDE + cc];
                g[d] += freq * (gs * cv - gc * sv);
            }
        }
        float gl = sqrtf(g[0] * g[0] + g[1] * g[1] + g[2] * g[2]);
        float invl = 1.f / (gl + 1e-10f);
        float nx = g[0] * invl, ny = g[1] * invl, nz = g[2] * invl;
        sm.nrm[s * 4 + 0] = nx; sm.nrm[s * 4 + 1] = ny; sm.nrm[s * 4 + 2] = nz;
        float dx = sm.dirs[s * 4 + 0], dy = sm.dirs[s * 4 + 1], dz = sm.dirs[s * 4 + 2];
        float dsdt = fminf(g[0] * dx + g[1] * dy + g[2] * dz, 0.f);
        float sdf = sm.feats[s * 16 + 0];
        float inv_s = __expf(s_var[0]);
        inv_s = fminf(fmaxf(inv_s, 1e-6f), 1e6f);
        float cdf = 1.f / (1.f + __expf(-inv_s * sdf));
        float rho = fmaxf(inv_s * (cdf - 1.f) * dsdt, 0.f);
        float alpha = 1.f - __expf(-rho * 0.005f);
        float a = fminf(fmaxf(alpha, 0.f), 1.f - 1e-7f);
        int n = n0 + s;
        if (n < Nsamp) {
            ws_a[n] = a;
            ws_nrm[n * 3 + 0] = nx; ws_nrm[n * 3 + 1] = ny; ws_nrm[n * 3 + 2] = nz;
        }
    }
    __syncthreads();

    // ---- P8a: cin = [dirs(3), feats(16), points(3), normal(3), 0pad..31]
    _Float16* cinh = sm.a0h;   // overlay (g1 dead)
    _Float16* cinl = sm.a0l;
    for (int i = tid; i < TILE * 32; i += NTHREADS) {
        int s = i >> 5, c = i & 31;
        float v = 0.f;
        if      (c < 3)  v = sm.dirs[s * 4 + c];
        else if (c < 19) v = sm.feats[s * 16 + (c - 3)];
        else if (c < 22) v = sm.pts[s * 4 + (c - 19)];
        else if (c < 25) v = sm.nrm[s * 4 + (c - 22)];
        splitst(v, &cinh[s * LDCIN + c], &cinl[s * LDCIN + c]);
    }
    __syncthreads();

    // ---- P8: hc = relu(cin @ Wc0 + bc0) -> act1 planes  (K pad 32)
    gemm32<2, true, true, false, false>(cinh, cinl, LDCIN,
                                        Wc0p, bc0, sm.a1h, sm.a1l, LDP, lane, w);
    __syncthreads();

    // ---- P9: rgb = sigmoid(hc @ Wc1 + bc1) (waves 0,1; 16x16 path)
    if (w < 2) {
        f32x4 acc = (f32x4){0.f, 0.f, 0.f, 0.f};
        const int m = w * 16 + (lane & 15);
        const int q8 = (lane >> 4) * 8;
        const _Float16* ahb = sm.a1h + m * LDP + q8;
        const _Float16* alb = sm.a1l + m * LDP + q8;
        const _Float16* bbase = Wc1p + lane * 16;
        half8 ax[2], ay[2], bh[2], bl[2];
        ax[0] = *(const half8*)ahb;
        ay[0] = *(const half8*)alb;
        bh[0] = *(const half8*)bbase;
        bl[0] = *(const half8*)(bbase + 8);
#pragma unroll
        for (int kit = 0; kit < 8; ++kit) {
            const int cur = kit & 1, nxt = cur ^ 1;
            if (kit + 1 < 8) {
                ax[nxt] = *(const half8*)(ahb + (kit + 1) * 32);
                ay[nxt] = *(const half8*)(alb + (kit + 1) * 32);
                const _Float16* bp = bbase + (kit + 1) * 1024;
                bh[nxt] = *(const half8*)bp;
                bl[nxt] = *(const half8*)(bp + 8);
            }
            __builtin_amdgcn_s_setprio(1);
            acc = __builtin_amdgcn_mfma_f32_16x16x32_f16(ay[cur], bh[cur], acc, 0, 0, 0);
            acc = __builtin_amdgcn_mfma_f32_16x16x32_f16(ax[cur], bl[cur], acc, 0, 0, 0);
            acc = __builtin_amdgcn_mfma_f32_16x16x32_f16(ax[cur], bh[cur], acc, 0, 0, 0);
            __builtin_amdgcn_s_setprio(0);
        }
        int col = lane & 15, q = lane >> 4;
        if (col < 3) {
#pragma unroll
            for (int r = 0; r < 4; ++r) {
                int s = w * 16 + q * 4 + r;
                float rgb = 1.f / (1.f + __expf(-(acc[r] + bc1[col])));
                int n = n0 + s;
                if (n < Nsamp) ws_rgb[n * 3 + col] = rgb;
            }
        }
    }
}

// ---------------- K3: per-ray compositing ----------------------------------
__global__ void k3_composite(
    const int* __restrict__ ray_idx, const float* __restrict__ t_starts,
    const float* __restrict__ ws_a, const float* __restrict__ ws_rgb,
    const float* __restrict__ ws_nrm,
    float* __restrict__ out_pc, float* __restrict__ out_pn,
    float* __restrict__ out_op, float* __restrict__ out_dp,
    float* __restrict__ out_w, int n_rays, int Nsamp)
{
    int r = blockIdx.x * blockDim.x + threadIdx.x;
    if (r >= n_rays) return;
    int lo = 0, hi = Nsamp;
    while (lo < hi) { int m = (lo + hi) >> 1; if (ray_idx[m] < r) lo = m + 1; else hi = m; }
    int start = lo;
    hi = Nsamp;
    while (lo < hi) { int m = (lo + hi) >> 1; if (ray_idx[m] < r + 1) lo = m + 1; else hi = m; }
    int end = lo;

    float T = 1.f, aco = 0.f, acd = 0.f;
    float c0 = 0.f, c1 = 0.f, c2 = 0.f, nx = 0.f, ny = 0.f, nz = 0.f;
    for (int n = start; n < end; ++n) {
        float a = ws_a[n];
        float wgt = a * T;
        T *= (1.f - a);
        out_w[n] = wgt;
        float mid = t_starts[n] + 0.0025f;
        aco += wgt; acd += wgt * mid;
        c0 += wgt * ws_rgb[n * 3 + 0];
        c1 += wgt * ws_rgb[n * 3 + 1];
        c2 += wgt * ws_rgb[n * 3 + 2];
        nx += wgt * ws_nrm[n * 3 + 0];
        ny += wgt * ws_nrm[n * 3 + 1];
        nz += wgt * ws_nrm[n * 3 + 2];
    }
    out_op[r] = aco;
    out_dp[r] = acd;
    out_pc[r * 3 + 0] = c0; out_pc[r * 3 + 1] = c1; out_pc[r * 3 + 2] = c2;
    float nl = sqrtf(nx * nx + ny * ny + nz * nz);
    float inv = 1.f / (nl + 1e-10f);
    out_pn[r * 3 + 0] = nx * inv; out_pn[r * 3 + 1] = ny * inv; out_pn[r * 3 + 2] = nz * inv;
}

// ---------------- K4: random_sdfs ------------------------------------------
__global__ __launch_bounds__(256) void k4_random(
    const float* __restrict__ pts,
    const float* __restrict__ Wg0, const float* __restrict__ bg0,
    const float* __restrict__ Wg1, const float* __restrict__ bg1,
    const float* __restrict__ Wg2, const float* __restrict__ bg2,
    float* __restrict__ out_rs, int n_rand)
{
    __shared__ float enc[40];
    __shared__ float h[256];
    __shared__ float red[256];
    int b = blockIdx.x;
    if (b >= n_rand) return;
    int tid = threadIdx.x;
    if (tid < 39) {
        int c = tid;
        float v;
        if (c < 3) v = pts[b * 3 + c];
        else {
            int e = c - 3, f = e / 6, r = e - f * 6;
            float freq = PI_F * (float)(1 << f);
            int d = (r < 3) ? r : r - 3;
            float x = pts[b * 3 + d];
            v = (r < 3) ? sinf(freq * x) : cosf(freq * x);
        }
        enc[c] = v;
    }
    __syncthreads();
    {
        float z = bg0[tid];
        for (int m = 0; m < 39; ++m) z += enc[m] * Wg0[m * 256 + tid];
        h[tid] = fmaxf(z, 0.f);
    }
    __syncthreads();
    {
        float z = bg1[tid];
        for (int k = 0; k < 256; ++k) z += h[k] * Wg1[k * 256 + tid];
        float h1 = fmaxf(z, 0.f);
        red[tid] = h1 * Wg2[tid * 16];   // Wg2[:,0]
    }
    __syncthreads();
    for (int off = 128; off > 0; off >>= 1) {
        if (tid < off) red[tid] += red[tid + off];
        __syncthreads();
    }
    if (tid == 0) out_rs[b] = red[0] + bg2[0];
}

extern "C" void kernel_launch(void* const* d_in, const int* in_sizes, int n_in,
                              void* d_out, int out_size, void* d_ws, size_t ws_size,
                              hipStream_t stream)
{
    const float* rays_o   = (const float*)d_in[0];
    const float* rays_d   = (const float*)d_in[1];
    const int*   ray_idx  = (const int*)  d_in[2];
    const float* t_starts = (const float*)d_in[3];
    const float* rpts     = (const float*)d_in[4];
    const float* s_var    = (const float*)d_in[5];
    const float* Wg0 = (const float*)d_in[6];  const float* bg0 = (const float*)d_in[7];
    const float* Wg1 = (const float*)d_in[8];  const float* bg1 = (const float*)d_in[9];
    const float* Wg2 = (const float*)d_in[10]; const float* bg2 = (const float*)d_in[11];
    const float* Wc0 = (const float*)d_in[12]; const float* bc0 = (const float*)d_in[13];
    const float* Wc1 = (const float*)d_in[14]; const float* bc1 = (const float*)d_in[15];

    const int n_rays = in_sizes[0] / 3;
    const int Ns     = in_sizes[2];
    const int n_rand = in_sizes[4] / 3;

    float* out  = (float*)d_out;
    float* o_pc = out;
    float* o_pn = out + (size_t)3 * n_rays;
    float* o_op = out + (size_t)6 * n_rays;
    float* o_dp = out + (size_t)7 * n_rays;
    float* o_w  = out + (size_t)8 * n_rays;
    float* o_sdf = o_w + Ns;
    float* o_rs  = o_sdf + Ns;

    // ws: packed f16 weights first, then float scratch
    _Float16* hptr  = (_Float16*)d_ws;
    _Float16* Wg0p  = hptr;                 // 32768 halves
    _Float16* Wg1p  = Wg0p  + 32768;        // 131072
    _Float16* Wg1Tp = Wg1p  + 131072;       // 131072
    _Float16* Wg0Tp = Wg1Tp + 131072;       // 32768
    _Float16* Wc0p  = Wg0Tp + 32768;        // 16384
    _Float16* Wg2p  = Wc0p  + 16384;        // 8192
    _Float16* Wc1p  = Wg2p  + 8192;         // 8192  -> total 360448 halves
    float* fbase  = (float*)(hptr + 360448);
    float* ws_a   = fbase;
    float* ws_rgb = ws_a + Ns;
    float* ws_nrm = ws_rgb + (size_t)3 * Ns;

    hipLaunchKernelGGL(k0_pack, dim3(704), dim3(256), 0, stream,
                       Wg0, Wg1, Wg2, Wc0, Wc1,
                       Wg0p, Wg1p, Wg1Tp, Wg0Tp, Wc0p, Wg2p, Wc1p);
    hipLaunchKernelGGL(k2_mlp, dim3((Ns + TILE - 1) / TILE), dim3(NTHREADS), 0, stream,
                       rays_o, rays_d, ray_idx, t_starts, s_var,
                       bg0, bg1, bg2, bc0, bc1,
                       Wg0p, Wg1p, Wg1Tp, Wg0Tp, Wc0p, Wg2p, Wc1p,
                       o_sdf, ws_a, ws_rgb, ws_nrm, Ns);
    hipLaunchKernelGGL(k4_random, dim3(n_rand), dim3(256), 0, stream,
                       rpts, Wg0, bg0, Wg1, bg1, Wg2, bg2, o_rs, n_rand);
    hipLaunchKernelGGL(k3_composite, dim3((n_rays + 255) / 256), dim3(256), 0, stream,
                       ray_idx, t_starts, ws_a, ws_rgb, ws_nrm,
                       o_pc, o_pn, o_op, o_dp, o_w, n_rays, Ns);
}

// Round 4
// 712.175 us; speedup vs baseline: 1.3567x; 1.0881x over previous
//
#include <hip/hip_runtime.h>
#include <math.h>

// ---------------------------------------------------------------------------
// NeuS-style fused renderer, R7.
//  - R6 failed absmax on pixels_normal (2.93e-2 > 2.91e-2): stacked 4 f16
//    quantization steps on the gradient path. R7 keeps ONE (P6 B hi-only,
//    the big MFMA saver) and restores the other three:
//      * P6 writes g1 lo-residual plane again (WLO=true)
//      * P7 back to full-split 3-MFMA (A hi+lo, B hi+lo, writes hi+lo)
//      * P7b reads g hi+lo
//  - Keeps R6 forward-path wins: P2 K-pad 48, double-angle trig, depth-3 B
//    prefetch, depth-2 A prefetch, s_setprio around MFMA clusters.
// ---------------------------------------------------------------------------

#define TILE 32
#define NTHREADS 512
#define LDP 264     // act plane stride (halves)
#define LDE 72      // enc plane stride (halves)
#define LDCIN 40    // cin plane stride (halves)
#define PI_F 3.14159265358979323846f

typedef _Float16 half8 __attribute__((ext_vector_type(8)));
typedef float f32x4 __attribute__((ext_vector_type(4)));
typedef float f32x16 __attribute__((ext_vector_type(16)));

struct alignas(16) SMemK2 {
    _Float16 a0h[TILE * LDP];   // h0 -> g1 -> cin(overlay)
    _Float16 a0l[TILE * LDP];
    _Float16 a1h[TILE * LDP];   // h1 -> g0(cols 0..63) -> hc
    _Float16 a1l[TILE * LDP];
    _Float16 ench[TILE * LDE];  // [x(3), sin/cos(36), 0-pad..47]
    _Float16 encl[TILE * LDE];
    float feats[TILE * 16];
    float pts [TILE * 4];
    float dirs[TILE * 4];
    float nrm [TILE * 4];
};  // 80384 B -> 2 blocks/CU

__device__ __forceinline__ void splitst(float v, _Float16* ph, _Float16* pl) {
    _Float16 h = (_Float16)v;
    *ph = h;
    *pl = (_Float16)(v - (float)h);
}

__device__ __forceinline__ f32x16 zero16() {
    f32x16 z;
#pragma unroll
    for (int i = 0; i < 16; ++i) z[i] = 0.f;
    return z;
}

// 32x32 output tile per wave, K = KITERS*16, cols nt*32..+32.
// A: split planes in LDS. B packed: hi8|lo8 per (nt,kit,lane).
// AMASK: A := (h1>0) ? 1 : 0 exactly (B carries w2c0 scaling); B hi-only
//        -> 1 MFMA per kit (rel err ~2^-11 on gradient, budget-checked).
// CMASK: epilogue gates by old C hi-plane sign (h0>0).
// WLO:   write lo residual plane.
template<int KITERS, bool BIAS, bool RELU, bool AMASK, bool CMASK, bool WLO>
__device__ __forceinline__ void gemm32(
    const _Float16* Ah, const _Float16* Al, const int lda,
    const _Float16* __restrict__ Bp, const float* __restrict__ bias,
    _Float16* Ch, _Float16* Cl, const int ldc,
    const int lane, const int nt)
{
    f32x16 acc0 = zero16(), acc1 = zero16();
    const int row  = lane & 31;
    const int koff = (lane >> 5) * 8;
    const _Float16* ahb = Ah + row * lda + koff;
    const _Float16* alb = Al + row * lda + koff;
    const _Float16* bbase = Bp + ((size_t)nt * KITERS * 64 + lane) * 16;

    half8 ax[2], ay[2];     // A depth-2 (LDS)
    half8 bh[3], bl[3];     // B depth-3 (global/L2)
    ax[0] = *(const half8*)ahb;
    if (!AMASK) ay[0] = *(const half8*)alb;
    bh[0] = *(const half8*)bbase;
    if (!AMASK) bl[0] = *(const half8*)(bbase + 8);
    if (KITERS > 1) {
        bh[1] = *(const half8*)(bbase + 1024);
        if (!AMASK) bl[1] = *(const half8*)(bbase + 1024 + 8);
    }

#pragma unroll
    for (int kit = 0; kit < KITERS; ++kit) {
        const int ac = kit & 1, an = ac ^ 1;
        const int bc = kit % 3;
        if (kit + 1 < KITERS) {
            ax[an] = *(const half8*)(ahb + (kit + 1) * 16);
            if (!AMASK) ay[an] = *(const half8*)(alb + (kit + 1) * 16);
        }
        if (kit + 2 < KITERS) {
            const int bn = (kit + 2) % 3;
            const _Float16* bp = bbase + (size_t)(kit + 2) * 1024;
            bh[bn] = *(const half8*)bp;
            if (!AMASK) bl[bn] = *(const half8*)(bp + 8);
        }
        f32x16& acc = ac ? acc1 : acc0;
        if (AMASK) {
            // exact 0/1 mask: relu clamps positives to >=1e-4, so
            // min(h*16384, 1) == 1 for h>=1e-4, == 0 for h==0.
            half8 m;
#pragma unroll
            for (int j = 0; j < 8; ++j) {
                _Float16 t = ax[ac][j] * (_Float16)16384.f;
                m[j] = (t < (_Float16)1.f) ? t : (_Float16)1.f;
            }
            __builtin_amdgcn_s_setprio(1);
            acc = __builtin_amdgcn_mfma_f32_32x32x16_f16(m, bh[bc], acc, 0, 0, 0);
            __builtin_amdgcn_s_setprio(0);
        } else {
            __builtin_amdgcn_s_setprio(1);
            acc = __builtin_amdgcn_mfma_f32_32x32x16_f16(ay[ac], bh[bc], acc, 0, 0, 0);
            acc = __builtin_amdgcn_mfma_f32_32x32x16_f16(ax[ac], bl[bc], acc, 0, 0, 0);
            acc = __builtin_amdgcn_mfma_f32_32x32x16_f16(ax[ac], bh[bc], acc, 0, 0, 0);
            __builtin_amdgcn_s_setprio(0);
        }
    }
    const int col = lane & 31;
    const int rb  = (lane >> 5) * 4;
    const int jc  = nt * 32 + col;
    const float bs = BIAS ? bias[jc] : 0.f;
#pragma unroll
    for (int r = 0; r < 16; ++r) {
        const int srow = (r & 3) + 8 * (r >> 2) + rb;
        float v = acc0[r] + acc1[r] + bs;
        if (RELU) v = (v > 0.f) ? fmaxf(v, 1e-4f) : 0.f;
        if (CMASK) { if (!((float)Ch[srow * ldc + jc] > 0.f)) v = 0.f; }
        _Float16 h = (_Float16)v;
        Ch[srow * ldc + jc] = h;
        if (WLO) Cl[srow * ldc + jc] = (_Float16)(v - (float)h);
    }
}

// 16x16 path (P7): rows mt*16..+16, cols (ntbase..+NTPW)*16, full split.
template<int KITERS, int NTPW>
__device__ __forceinline__ void gemm16(
    const _Float16* Ah, const _Float16* Al, const int lda,
    const _Float16* __restrict__ Bp,
    _Float16* Ch, _Float16* Cl, const int ldc,
    const int lane, const int mt, const int ntbase)
{
    f32x4 acc[NTPW];
#pragma unroll
    for (int t = 0; t < NTPW; ++t) acc[t] = (f32x4){0.f, 0.f, 0.f, 0.f};
    const int m  = mt * 16 + (lane & 15);
    const int q8 = (lane >> 4) * 8;
    const _Float16* ahb = Ah + m * lda + q8;
    const _Float16* alb = Al + m * lda + q8;
    const _Float16* bbase = Bp + ((size_t)ntbase * KITERS * 64 + lane) * 16;

    half8 ax[2], ay[2], bh[3][NTPW], bl[3][NTPW];
    ax[0] = *(const half8*)ahb;
    ay[0] = *(const half8*)alb;
#pragma unroll
    for (int t = 0; t < NTPW; ++t) {
        const _Float16* bt = bbase + (size_t)t * KITERS * 1024;
        bh[0][t] = *(const half8*)bt;
        bl[0][t] = *(const half8*)(bt + 8);
    }
    if (KITERS > 1) {
#pragma unroll
        for (int t = 0; t < NTPW; ++t) {
            const _Float16* bt = bbase + 1024 + (size_t)t * KITERS * 1024;
            bh[1][t] = *(const half8*)bt;
            bl[1][t] = *(const half8*)(bt + 8);
        }
    }
#pragma unroll
    for (int kit = 0; kit < KITERS; ++kit) {
        const int ac = kit & 1, an = ac ^ 1;
        const int bc = kit % 3;
        if (kit + 1 < KITERS) {
            ax[an] = *(const half8*)(ahb + (kit + 1) * 32);
            ay[an] = *(const half8*)(alb + (kit + 1) * 32);
        }
        if (kit + 2 < KITERS) {
            const int bn = (kit + 2) % 3;
            const _Float16* bp = bbase + (size_t)(kit + 2) * 1024;
#pragma unroll
            for (int t = 0; t < NTPW; ++t) {
                const _Float16* bt = bp + (size_t)t * KITERS * 1024;
                bh[bn][t] = *(const half8*)bt;
                bl[bn][t] = *(const half8*)(bt + 8);
            }
        }
        __builtin_amdgcn_s_setprio(1);
#pragma unroll
        for (int t = 0; t < NTPW; ++t) {
            acc[t] = __builtin_amdgcn_mfma_f32_16x16x32_f16(ay[ac], bh[bc][t], acc[t], 0, 0, 0);
            acc[t] = __builtin_amdgcn_mfma_f32_16x16x32_f16(ax[ac], bl[bc][t], acc[t], 0, 0, 0);
            acc[t] = __builtin_amdgcn_mfma_f32_16x16x32_f16(ax[ac], bh[bc][t], acc[t], 0, 0, 0);
        }
        __builtin_amdgcn_s_setprio(0);
    }
    const int col = lane & 15, q = lane >> 4;
#pragma unroll
    for (int t = 0; t < NTPW; ++t) {
        const int j = (ntbase + t) * 16 + col;
#pragma unroll
        for (int r = 0; r < 4; ++r) {
            const int s = mt * 16 + q * 4 + r;
            float v = acc[t][r];
            _Float16 h = (_Float16)v;
            Ch[s * ldc + j] = h;
            Cl[s * ldc + j] = (_Float16)(v - (float)h);
        }
    }
}

// ---------------- K0: pack weights to hi|lo B-fragment layouts --------------
// modes 0,1,2,4 -> 32x32x16 layout; modes 3,5,6 -> 16x16x32 layout.
// mode 2 (Wg1T) is pre-scaled by Wg2[:,0] so P6's A can be a pure 0/1 mask.
__global__ __launch_bounds__(256) void k0_pack(
    const float* __restrict__ Wg0, const float* __restrict__ Wg1,
    const float* __restrict__ Wg2, const float* __restrict__ Wc0,
    const float* __restrict__ Wc1,
    _Float16* __restrict__ Wg0p, _Float16* __restrict__ Wg1p,
    _Float16* __restrict__ Wg1Tp, _Float16* __restrict__ Wg0Tp,
    _Float16* __restrict__ Wc0p, _Float16* __restrict__ Wg2p,
    _Float16* __restrict__ Wc1p)
{
    int gid = blockIdx.x * 256 + threadIdx.x;
    if (gid >= 176128) return;
    int idx, kiters, mode;
    _Float16* dst;
    if      (gid <  12288) { idx = gid;          kiters = 3;  dst = Wg0p;  mode = 0; }
    else if (gid <  77824) { idx = gid -  12288; kiters = 16; dst = Wg1p;  mode = 1; }
    else if (gid < 143360) { idx = gid -  77824; kiters = 16; dst = Wg1Tp; mode = 2; }
    else if (gid < 159744) { idx = gid - 143360; kiters = 8;  dst = Wg0Tp; mode = 3; }
    else if (gid < 167936) { idx = gid - 159744; kiters = 2;  dst = Wc0p;  mode = 4; }
    else if (gid < 172032) { idx = gid - 167936; kiters = 8;  dst = Wg2p;  mode = 5; }
    else                   { idx = gid - 172032; kiters = 8;  dst = Wc1p;  mode = 6; }
    const bool p32 = (mode == 0 || mode == 1 || mode == 2 || mode == 4);
    int j = idx & 7, lane = (idx >> 3) & 63, rest = idx >> 9;
    int kit = rest % kiters, nt = rest / kiters;
    int k, n;
    if (p32) { k = kit * 16 + ((lane >> 5) << 3) + j; n = (nt << 5) + (lane & 31); }
    else     { k = kit * 32 + ((lane >> 4) << 3) + j; n = (nt << 4) + (lane & 15); }
    float val = 0.f;
    switch (mode) {
        case 0: val = (k < 39) ? Wg0[k * 256 + n] : 0.f; break;
        case 1: val = Wg1[k * 256 + n]; break;
        case 2: val = Wg1[n * 256 + k] * Wg2[k * 16]; break;    // Wg1^T * w2c0
        case 3: val = (n < 39) ? Wg0[n * 256 + k] : 0.f; break; // Wg0^T
        case 4: val = (k < 25) ? Wc0[k * 256 + n] : 0.f; break;
        case 5: val = Wg2[k * 16 + n]; break;
        case 6: val = (n < 3) ? Wc1[k * 3 + n] : 0.f; break;
    }
    _Float16 h = (_Float16)val;
    _Float16 l = (_Float16)(val - (float)h);
    int off = ((nt * kiters + kit) * 64 + lane) * 16 + j;
    dst[off] = h;
    dst[off + 8] = l;
}

// ---------------- K2: the fused MLP (8 waves) ------------------------------
__global__ __launch_bounds__(512, 4) void k2_mlp(
    const float* __restrict__ rays_o, const float* __restrict__ rays_d,
    const int*   __restrict__ ray_idx, const float* __restrict__ t_starts,
    const float* __restrict__ s_var,
    const float* __restrict__ bg0, const float* __restrict__ bg1,
    const float* __restrict__ bg2,
    const float* __restrict__ bc0, const float* __restrict__ bc1,
    const _Float16* __restrict__ Wg0p, const _Float16* __restrict__ Wg1p,
    const _Float16* __restrict__ Wg1Tp, const _Float16* __restrict__ Wg0Tp,
    const _Float16* __restrict__ Wc0p, const _Float16* __restrict__ Wg2p,
    const _Float16* __restrict__ Wc1p,
    float* __restrict__ out_sdf, float* __restrict__ ws_a,
    float* __restrict__ ws_rgb, float* __restrict__ ws_nrm,
    int Nsamp)
{
    __shared__ SMemK2 sm;
    const int tid = threadIdx.x;
    const int lane = tid & 63;
    const int w = tid >> 6;          // 0..7
    const int n0 = blockIdx.x * TILE;

    // ---- P0: points, dirs
    if (tid < TILE) {
        int n = n0 + tid; if (n >= Nsamp) n = Nsamp - 1;
        int ri = ray_idx[n];
        float dx = rays_d[ri * 3 + 0], dy = rays_d[ri * 3 + 1], dz = rays_d[ri * 3 + 2];
        float inv = 1.f / (sqrtf(dx * dx + dy * dy + dz * dz) + 1e-10f);
        dx *= inv; dy *= inv; dz *= inv;
        float mid = t_starts[n] + 0.0025f;
        sm.dirs[tid * 4 + 0] = dx; sm.dirs[tid * 4 + 1] = dy; sm.dirs[tid * 4 + 2] = dz;
        float px = rays_o[ri * 3 + 0] + dx * mid;
        float py = rays_o[ri * 3 + 1] + dy * mid;
        float pz = rays_o[ri * 3 + 2] + dz * mid;
        sm.pts[tid * 4 + 0] = px; sm.pts[tid * 4 + 1] = py; sm.pts[tid * 4 + 2] = pz;
        splitst(px, &sm.ench[tid * LDE + 0], &sm.encl[tid * LDE + 0]);
        splitst(py, &sm.ench[tid * LDE + 1], &sm.encl[tid * LDE + 1]);
        splitst(pz, &sm.ench[tid * LDE + 2], &sm.encl[tid * LDE + 2]);
    }
    __syncthreads();

    // ---- P1: positional encoding via double-angle recurrence.
    for (int i = tid; i < TILE * 3; i += NTHREADS) {
        int s = i & 31;
        int d = i >> 5;        // 0..2
        float x = sm.pts[s * 4 + d];
        float a = PI_F * x;
        float sv = sinf(a), cv = cosf(a);
#pragma unroll
        for (int f = 0; f < 6; ++f) {
            splitst(sv, &sm.ench[s * LDE + 3 + f * 6 + d],     &sm.encl[s * LDE + 3 + f * 6 + d]);
            splitst(cv, &sm.ench[s * LDE + 3 + f * 6 + 3 + d], &sm.encl[s * LDE + 3 + f * 6 + 3 + d]);
            float s2 = 2.f * sv * cv;
            float c2 = 1.f - 2.f * sv * sv;
            sv = s2; cv = c2;
        }
    }
    for (int i = tid; i < TILE * 9; i += NTHREADS) {   // pad cols 39..47
        int s = i / 9, c = 39 + (i - s * 9);
        sm.ench[s * LDE + c] = (_Float16)0.f;
        sm.encl[s * LDE + c] = (_Float16)0.f;
    }
    __syncthreads();

    // ---- P2: h0 = relu(enc @ Wg0 + bg0) -> act0 planes   (K pad 48)
    gemm32<3, true, true, false, false, true>(sm.ench, sm.encl, LDE,
                                              Wg0p, bg0, sm.a0h, sm.a0l, LDP, lane, w);
    __syncthreads();

    // ---- P3: h1 = relu(h0 @ Wg1 + bg1) -> act1 planes
    gemm32<16, true, true, false, false, true>(sm.a0h, sm.a0l, LDP,
                                               Wg1p, bg1, sm.a1h, sm.a1l, LDP, lane, w);
    __syncthreads();

    // ---- P4: feats = h1 @ Wg2 + bg2 (waves 0,1; 16x16 path); sdf out
    if (w < 2) {
        f32x4 acc = (f32x4){0.f, 0.f, 0.f, 0.f};
        const int m = w * 16 + (lane & 15);
        const int q8 = (lane >> 4) * 8;
        const _Float16* ahb = sm.a1h + m * LDP + q8;
        const _Float16* alb = sm.a1l + m * LDP + q8;
        const _Float16* bbase = Wg2p + lane * 16;
        half8 ax[2], ay[2], bh[2], bl[2];
        ax[0] = *(const half8*)ahb;
        ay[0] = *(const half8*)alb;
        bh[0] = *(const half8*)bbase;
        bl[0] = *(const half8*)(bbase + 8);
#pragma unroll
        for (int kit = 0; kit < 8; ++kit) {
            const int cur = kit & 1, nxt = cur ^ 1;
            if (kit + 1 < 8) {
                ax[nxt] = *(const half8*)(ahb + (kit + 1) * 32);
                ay[nxt] = *(const half8*)(alb + (kit + 1) * 32);
                const _Float16* bp = bbase + (kit + 1) * 1024;
                bh[nxt] = *(const half8*)bp;
                bl[nxt] = *(const half8*)(bp + 8);
            }
            __builtin_amdgcn_s_setprio(1);
            acc = __builtin_amdgcn_mfma_f32_16x16x32_f16(ay[cur], bh[cur], acc, 0, 0, 0);
            acc = __builtin_amdgcn_mfma_f32_16x16x32_f16(ax[cur], bl[cur], acc, 0, 0, 0);
            acc = __builtin_amdgcn_mfma_f32_16x16x32_f16(ax[cur], bh[cur], acc, 0, 0, 0);
            __builtin_amdgcn_s_setprio(0);
        }
        int col = lane & 15, q = lane >> 4;
        float bs = bg2[col];
#pragma unroll
        for (int r = 0; r < 4; ++r) {
            int s = w * 16 + q * 4 + r;
            float vv = acc[r] + bs;
            sm.feats[s * 16 + col] = vv;
            if (col == 0) { int n = n0 + s; if (n < Nsamp) out_sdf[n] = vv; }
        }
    }
    // no barrier: P6 reads a1 planes (stable); each wave's P6 output tile only
    // masks against h0 cells it wrote itself in P2.

    // ---- P6: g1 = mask(h1) @ (Wg1T*w2c0)_hi, gated by (h0>0) -> a0 planes
    gemm32<16, false, false, true, true, true>(sm.a1h, sm.a1l, LDP,
                                               Wg1Tp, nullptr, sm.a0h, sm.a0l, LDP, lane, w);
    __syncthreads();

    // ---- P7: g0 = g1 @ Wg0T -> a1 planes cols 0..63 (39 valid), full split
    gemm16<8, 1>(sm.a0h, sm.a0l, LDP, Wg0Tp,
                 sm.a1h, sm.a1l, LDP, lane, w & 1, w >> 1);
    __syncthreads();

    // ---- P7b: grad through encoding, normal, alpha
    if (tid < TILE) {
        int s = tid;
        float g[3];
#pragma unroll
        for (int d = 0; d < 3; ++d)
            g[d] = (float)sm.a1h[s * LDP + d] + (float)sm.a1l[s * LDP + d];
#pragma unroll
        for (int f = 0; f < 6; ++f) {
            float freq = PI_F * (float)(1 << f);
#pragma unroll
            for (int d = 0; d < 3; ++d) {
                int cs = 3 + f * 6 + d, cc = cs + 3;
                float gs = (float)sm.a1h[s * LDP + cs] + (float)sm.a1l[s * LDP + cs];
                float gc = (float)sm.a1h[s * LDP + cc] + (float)sm.a1l[s * LDP + cc];
                float sv = (float)sm.ench[s * LDE + cs] + (float)sm.encl[s * LDE + cs];
                float cv = (float)sm.ench[s * LDE + cc] + (float)sm.encl[s * LDE + cc];
                g[d] += freq * (gs * cv - gc * sv);
            }
        }
        float gl = sqrtf(g[0] * g[0] + g[1] * g[1] + g[2] * g[2]);
        float invl = 1.f / (gl + 1e-10f);
        float nx = g[0] * invl, ny = g[1] * invl, nz = g[2] * invl;
        sm.nrm[s * 4 + 0] = nx; sm.nrm[s * 4 + 1] = ny; sm.nrm[s * 4 + 2] = nz;
        float dx = sm.dirs[s * 4 + 0], dy = sm.dirs[s * 4 + 1], dz = sm.dirs[s * 4 + 2];
        float dsdt = fminf(g[0] * dx + g[1] * dy + g[2] * dz, 0.f);
        float sdf = sm.feats[s * 16 + 0];
        float inv_s = __expf(s_var[0]);
        inv_s = fminf(fmaxf(inv_s, 1e-6f), 1e6f);
        float cdf = 1.f / (1.f + __expf(-inv_s * sdf));
        float rho = fmaxf(inv_s * (cdf - 1.f) * dsdt, 0.f);
        float alpha = 1.f - __expf(-rho * 0.005f);
        float a = fminf(fmaxf(alpha, 0.f), 1.f - 1e-7f);
        int n = n0 + s;
        if (n < Nsamp) {
            ws_a[n] = a;
            ws_nrm[n * 3 + 0] = nx; ws_nrm[n * 3 + 1] = ny; ws_nrm[n * 3 + 2] = nz;
        }
    }
    __syncthreads();

    // ---- P8a: cin = [dirs(3), feats(16), points(3), normal(3), 0pad..31]
    _Float16* cinh = sm.a0h;   // overlay (g1 dead)
    _Float16* cinl = sm.a0l;
    for (int i = tid; i < TILE * 32; i += NTHREADS) {
        int s = i >> 5, c = i & 31;
        float v = 0.f;
        if      (c < 3)  v = sm.dirs[s * 4 + c];
        else if (c < 19) v = sm.feats[s * 16 + (c - 3)];
        else if (c < 22) v = sm.pts[s * 4 + (c - 19)];
        else if (c < 25) v = sm.nrm[s * 4 + (c - 22)];
        splitst(v, &cinh[s * LDCIN + c], &cinl[s * LDCIN + c]);
    }
    __syncthreads();

    // ---- P8: hc = relu(cin @ Wc0 + bc0) -> act1 planes  (K pad 32)
    gemm32<2, true, true, false, false, true>(cinh, cinl, LDCIN,
                                              Wc0p, bc0, sm.a1h, sm.a1l, LDP, lane, w);
    __syncthreads();

    // ---- P9: rgb = sigmoid(hc @ Wc1 + bc1) (waves 0,1; 16x16 path)
    if (w < 2) {
        f32x4 acc = (f32x4){0.f, 0.f, 0.f, 0.f};
        const int m = w * 16 + (lane & 15);
        const int q8 = (lane >> 4) * 8;
        const _Float16* ahb = sm.a1h + m * LDP + q8;
        const _Float16* alb = sm.a1l + m * LDP + q8;
        const _Float16* bbase = Wc1p + lane * 16;
        half8 ax[2], ay[2], bh[2], bl[2];
        ax[0] = *(const half8*)ahb;
        ay[0] = *(const half8*)alb;
        bh[0] = *(const half8*)bbase;
        bl[0] = *(const half8*)(bbase + 8);
#pragma unroll
        for (int kit = 0; kit < 8; ++kit) {
            const int cur = kit & 1, nxt = cur ^ 1;
            if (kit + 1 < 8) {
                ax[nxt] = *(const half8*)(ahb + (kit + 1) * 32);
                ay[nxt] = *(const half8*)(alb + (kit + 1) * 32);
                const _Float16* bp = bbase + (kit + 1) * 1024;
                bh[nxt] = *(const half8*)bp;
                bl[nxt] = *(const half8*)(bp + 8);
            }
            __builtin_amdgcn_s_setprio(1);
            acc = __builtin_amdgcn_mfma_f32_16x16x32_f16(ay[cur], bh[cur], acc, 0, 0, 0);
            acc = __builtin_amdgcn_mfma_f32_16x16x32_f16(ax[cur], bl[cur], acc, 0, 0, 0);
            acc = __builtin_amdgcn_mfma_f32_16x16x32_f16(ax[cur], bh[cur], acc, 0, 0, 0);
            __builtin_amdgcn_s_setprio(0);
        }
        int col = lane & 15, q = lane >> 4;
        if (col < 3) {
#pragma unroll
            for (int r = 0; r < 4; ++r) {
                int s = w * 16 + q * 4 + r;
                float rgb = 1.f / (1.f + __expf(-(acc[r] + bc1[col])));
                int n = n0 + s;
                if (n < Nsamp) ws_rgb[n * 3 + col] = rgb;
            }
        }
    }
}

// ---------------- K3: per-ray compositing ----------------------------------
__global__ void k3_composite(
    const int* __restrict__ ray_idx, const float* __restrict__ t_starts,
    const float* __restrict__ ws_a, const float* __restrict__ ws_rgb,
    const float* __restrict__ ws_nrm,
    float* __restrict__ out_pc, float* __restrict__ out_pn,
    float* __restrict__ out_op, float* __restrict__ out_dp,
    float* __restrict__ out_w, int n_rays, int Nsamp)
{
    int r = blockIdx.x * blockDim.x + threadIdx.x;
    if (r >= n_rays) return;
    int lo = 0, hi = Nsamp;
    while (lo < hi) { int m = (lo + hi) >> 1; if (ray_idx[m] < r) lo = m + 1; else hi = m; }
    int start = lo;
    hi = Nsamp;
    while (lo < hi) { int m = (lo + hi) >> 1; if (ray_idx[m] < r + 1) lo = m + 1; else hi = m; }
    int end = lo;

    float T = 1.f, aco = 0.f, acd = 0.f;
    float c0 = 0.f, c1 = 0.f, c2 = 0.f, nx = 0.f, ny = 0.f, nz = 0.f;
    for (int n = start; n < end; ++n) {
        float a = ws_a[n];
        float wgt = a * T;
        T *= (1.f - a);
        out_w[n] = wgt;
        float mid = t_starts[n] + 0.0025f;
        aco += wgt; acd += wgt * mid;
        c0 += wgt * ws_rgb[n * 3 + 0];
        c1 += wgt * ws_rgb[n * 3 + 1];
        c2 += wgt * ws_rgb[n * 3 + 2];
        nx += wgt * ws_nrm[n * 3 + 0];
        ny += wgt * ws_nrm[n * 3 + 1];
        nz += wgt * ws_nrm[n * 3 + 2];
    }
    out_op[r] = aco;
    out_dp[r] = acd;
    out_pc[r * 3 + 0] = c0; out_pc[r * 3 + 1] = c1; out_pc[r * 3 + 2] = c2;
    float nl = sqrtf(nx * nx + ny * ny + nz * nz);
    float inv = 1.f / (nl + 1e-10f);
    out_pn[r * 3 + 0] = nx * inv; out_pn[r * 3 + 1] = ny * inv; out_pn[r * 3 + 2] = nz * inv;
}

// ---------------- K4: random_sdfs ------------------------------------------
__global__ __launch_bounds__(256) void k4_random(
    const float* __restrict__ pts,
    const float* __restrict__ Wg0, const float* __restrict__ bg0,
    const float* __restrict__ Wg1, const float* __restrict__ bg1,
    const float* __restrict__ Wg2, const float* __restrict__ bg2,
    float* __restrict__ out_rs, int n_rand)
{
    __shared__ float enc[40];
    __shared__ float h[256];
    __shared__ float red[256];
    int b = blockIdx.x;
    if (b >= n_rand) return;
    int tid = threadIdx.x;
    if (tid < 39) {
        int c = tid;
        float v;
        if (c < 3) v = pts[b * 3 + c];
        else {
            int e = c - 3, f = e / 6, r = e - f * 6;
            float freq = PI_F * (float)(1 << f);
            int d = (r < 3) ? r : r - 3;
            float x = pts[b * 3 + d];
            v = (r < 3) ? sinf(freq * x) : cosf(freq * x);
        }
        enc[c] = v;
    }
    __syncthreads();
    {
        float z = bg0[tid];
        for (int m = 0; m < 39; ++m) z += enc[m] * Wg0[m * 256 + tid];
        h[tid] = fmaxf(z, 0.f);
    }
    __syncthreads();
    {
        float z = bg1[tid];
        for (int k = 0; k < 256; ++k) z += h[k] * Wg1[k * 256 + tid];
        float h1 = fmaxf(z, 0.f);
        red[tid] = h1 * Wg2[tid * 16];   // Wg2[:,0]
    }
    __syncthreads();
    for (int off = 128; off > 0; off >>= 1) {
        if (tid < off) red[tid] += red[tid + off];
        __syncthreads();
    }
    if (tid == 0) out_rs[b] = red[0] + bg2[0];
}

extern "C" void kernel_launch(void* const* d_in, const int* in_sizes, int n_in,
                              void* d_out, int out_size, void* d_ws, size_t ws_size,
                              hipStream_t stream)
{
    const float* rays_o   = (const float*)d_in[0];
    const float* rays_d   = (const float*)d_in[1];
    const int*   ray_idx  = (const int*)  d_in[2];
    const float* t_starts = (const float*)d_in[3];
    const float* rpts     = (const float*)d_in[4];
    const float* s_var    = (const float*)d_in[5];
    const float* Wg0 = (const float*)d_in[6];  const float* bg0 = (const float*)d_in[7];
    const float* Wg1 = (const float*)d_in[8];  const float* bg1 = (const float*)d_in[9];
    const float* Wg2 = (const float*)d_in[10]; const float* bg2 = (const float*)d_in[11];
    const float* Wc0 = (const float*)d_in[12]; const float* bc0 = (const float*)d_in[13];
    const float* Wc1 = (const float*)d_in[14]; const float* bc1 = (const float*)d_in[15];

    const int n_rays = in_sizes[0] / 3;
    const int Ns     = in_sizes[2];
    const int n_rand = in_sizes[4] / 3;

    float* out  = (float*)d_out;
    float* o_pc = out;
    float* o_pn = out + (size_t)3 * n_rays;
    float* o_op = out + (size_t)6 * n_rays;
    float* o_dp = out + (size_t)7 * n_rays;
    float* o_w  = out + (size_t)8 * n_rays;
    float* o_sdf = o_w + Ns;
    float* o_rs  = o_sdf + Ns;

    // ws: packed f16 weights first, then float scratch
    _Float16* hptr  = (_Float16*)d_ws;
    _Float16* Wg0p  = hptr;                 // 24576 halves (8nt x 3kit)
    _Float16* Wg1p  = Wg0p  + 24576;        // 131072
    _Float16* Wg1Tp = Wg1p  + 131072;       // 131072
    _Float16* Wg0Tp = Wg1Tp + 131072;       // 32768
    _Float16* Wc0p  = Wg0Tp + 32768;        // 16384
    _Float16* Wg2p  = Wc0p  + 16384;        // 8192
    _Float16* Wc1p  = Wg2p  + 8192;         // 8192  -> total 352256 halves
    float* fbase  = (float*)(hptr + 352256);
    float* ws_a   = fbase;
    float* ws_rgb = ws_a + Ns;
    float* ws_nrm = ws_rgb + (size_t)3 * Ns;

    hipLaunchKernelGGL(k0_pack, dim3(688), dim3(256), 0, stream,
                       Wg0, Wg1, Wg2, Wc0, Wc1,
                       Wg0p, Wg1p, Wg1Tp, Wg0Tp, Wc0p, Wg2p, Wc1p);
    hipLaunchKernelGGL(k2_mlp, dim3((Ns + TILE - 1) / TILE), dim3(NTHREADS), 0, stream,
                       rays_o, rays_d, ray_idx, t_starts, s_var,
                       bg0, bg1, bg2, bc0, bc1,
                       Wg0p, Wg1p, Wg1Tp, Wg0Tp, Wc0p, Wg2p, Wc1p,
                       o_sdf, ws_a, ws_rgb, ws_nrm, Ns);
    hipLaunchKernelGGL(k4_random, dim3(n_rand), dim3(256), 0, stream,
                       rpts, Wg0, bg0, Wg1, bg1, Wg2, bg2, o_rs, n_rand);
    hipLaunchKernelGGL(k3_composite, dim3((n_rays + 255) / 256), dim3(256), 0, stream,
                       ray_idx, t_starts, ws_a, ws_rgb, ws_nrm,
                       o_pc, o_pn, o_op, o_dp, o_w, n_rays, Ns);
}